// Round 3
// baseline (383.075 us; speedup 1.0000x reference)
//
#include <hip/hip_runtime.h>

#define BB 32
#define NHH 32
#define NKVV 8
#define HDD 128
#define SWW 4096
#define DD 4096
#define GG 4
#define QKVC 6144
#define NSPLIT 16
#define CHUNK (SWW / NSPLIT)  // 256
#define KSPB 16

// ============ split-K skinny GEMM partial: part[ky][32][ncols] ==============
__global__ __launch_bounds__(256) void skinny_gemm_part(
    const float* __restrict__ x, const float* __restrict__ w,
    float* __restrict__ part, int K, int ncols) {
  __shared__ float2 red[4][64][8];
  const int t = threadIdx.x;
  const int ct = t & 63, kg = t >> 6;
  const long c0 = (long)blockIdx.x * 128 + ct * 2;
  const int Kb = K / KSPB;
  const int klen = Kb / 4;
  const int k0 = blockIdx.y * Kb + kg * klen;
  float2 acc[BB];
#pragma unroll
  for (int r = 0; r < BB; ++r) acc[r] = make_float2(0.f, 0.f);

#pragma unroll 2
  for (int k = k0; k < k0 + klen; k += 4) {
    float2 wv0 = *(const float2*)&w[(long)(k + 0) * ncols + c0];
    float2 wv1 = *(const float2*)&w[(long)(k + 1) * ncols + c0];
    float2 wv2 = *(const float2*)&w[(long)(k + 2) * ncols + c0];
    float2 wv3 = *(const float2*)&w[(long)(k + 3) * ncols + c0];
#pragma unroll
    for (int r = 0; r < BB; ++r) {
      float4 xv = *(const float4*)&x[r * K + k];
      acc[r].x = fmaf(xv.x, wv0.x, acc[r].x);
      acc[r].y = fmaf(xv.x, wv0.y, acc[r].y);
      acc[r].x = fmaf(xv.y, wv1.x, acc[r].x);
      acc[r].y = fmaf(xv.y, wv1.y, acc[r].y);
      acc[r].x = fmaf(xv.z, wv2.x, acc[r].x);
      acc[r].y = fmaf(xv.z, wv2.y, acc[r].y);
      acc[r].x = fmaf(xv.w, wv3.x, acc[r].x);
      acc[r].y = fmaf(xv.w, wv3.y, acc[r].y);
    }
  }
  for (int rc = 0; rc < 4; ++rc) {
    if (rc) __syncthreads();
#pragma unroll
    for (int j = 0; j < 8; ++j) red[kg][ct][j] = acc[rc * 8 + j];
    __syncthreads();
    if (kg == 0) {
#pragma unroll
      for (int j = 0; j < 8; ++j) {
        float2 s0 = red[0][ct][j], s1 = red[1][ct][j];
        float2 s2 = red[2][ct][j], s3 = red[3][ct][j];
        float2 sm = make_float2((s0.x + s1.x) + (s2.x + s3.x),
                                (s0.y + s1.y) + (s2.y + s3.y));
        *(float2*)&part[((long)blockIdx.y * BB + rc * 8 + j) * ncols + c0] = sm;
      }
    }
  }
}

// ============ reduce split-K partials =======================================
__global__ __launch_bounds__(256) void reduce_part(
    const float* __restrict__ part, float* __restrict__ out, long n) {
  long i = (long)blockIdx.x * 256 + threadIdx.x;
  if (i >= n) return;
  float s = 0.f;
#pragma unroll
  for (int j = 0; j < KSPB; ++j) s += part[(long)j * n + i];
  out[i] = s;
}

// ============ rotary ========================================================
__global__ __launch_bounds__(128) void rotary_kernel(
    const float* __restrict__ xqkv, const float* __restrict__ rot,
    float* __restrict__ q_rot, float* __restrict__ k_rot) {
  __shared__ float vec[HDD];
  const int blk = blockIdx.x;
  const int j = threadIdx.x;
  const float* src;
  float* dst;
  if (blk < BB * NHH) {
    int b = blk >> 5, h = blk & 31;
    src = xqkv + (long)b * QKVC + h * HDD;
    dst = q_rot + (long)(b * NHH + h) * HDD;
  } else {
    int i = blk - BB * NHH;
    int b = i >> 3, kv = i & 7;
    src = xqkv + (long)b * QKVC + NHH * HDD + kv * HDD;
    dst = k_rot + (long)(b * NKVV + kv) * HDD;
  }
  vec[j] = src[j];
  __syncthreads();
  float a0 = 0.f, a1 = 0.f, a2 = 0.f, a3 = 0.f;
#pragma unroll
  for (int d0 = 0; d0 < HDD; d0 += 4) {
    a0 += vec[d0 + 0] * rot[(d0 + 0) * HDD + j];
    a1 += vec[d0 + 1] * rot[(d0 + 1) * HDD + j];
    a2 += vec[d0 + 2] * rot[(d0 + 2) * HDD + j];
    a3 += vec[d0 + 3] * rot[(d0 + 3) * HDD + j];
  }
  dst[j] = (a0 + a1) + (a2 + a3);
}

// ============ fused single-pass flash-decode (one KV split) =================
// 4 waves/block; wave owns 64 contiguous keys; online softmax in registers.
__global__ __launch_bounds__(256) void attn_fused(
    const float* __restrict__ q_rot, const float* __restrict__ k_rot,
    const float* __restrict__ xqkv, const float* __restrict__ cache_k,
    const float* __restrict__ cache_v, const float* __restrict__ mask,
    const int* __restrict__ curpos, float* __restrict__ pm,
    float* __restrict__ pl, float* __restrict__ pacc) {
  __shared__ float4 mkp[CHUNK];        // mask [sl] -> 4 g
  __shared__ float wacc[4][GG][HDD];   // per-wave PV partials
  __shared__ float wml[4][GG][2];      // per-wave (m, l)

  const int blk = blockIdx.x;
  const int split = blk & (NSPLIT - 1);
  const int bkv = blk >> 4;
  const int b = bkv >> 3, kv = bkv & 7;
  const int cur = curpos[0];
  const int s0 = split * CHUNK;
  const int t = threadIdx.x, lane = t & 63, w = t >> 6;
  const int lg = lane & 15;
  const int grp = lane >> 4;  // which of the 4 keys this lane group handles
  const float scale = 0.08838834764831845f;  // 1/sqrt(128)

  // mask -> LDS (coalesced global reads)
  for (int i = t; i < GG * CHUNK; i += 256) {
    int g = i >> 8;
    int sl = i & (CHUNK - 1);
    ((float*)mkp)[sl * 4 + g] =
        mask[((long)(kv * GG + g) * BB + b) * SWW + s0 + sl];
  }

  // Q fragments: lane lg holds dims [lg*4..+3] and [64+lg*4..+3]
  float4 qa[GG], qb[GG];
#pragma unroll
  for (int g = 0; g < GG; ++g) {
    const float4* qp =
        (const float4*)(q_rot + (long)((b * NHH + kv * GG + g) * HDD));
    qa[g] = qp[lg];
    qb[g] = qp[lg + 16];
  }
  const float* kbase = cache_k + (long)(b * NKVV + kv) * SWW * HDD;
  const float* knew = k_rot + (long)(b * NKVV + kv) * HDD;
  const float* vbase = cache_v + (long)(b * NKVV + kv) * SWW * HDD;
  const float* vnew = xqkv + (long)b * QKVC + NHH * HDD + NKVV * HDD + kv * HDD;
  __syncthreads();

  float m0 = -1e30f, m1 = -1e30f, m2 = -1e30f, m3 = -1e30f;
  float l0 = 0.f, l1 = 0.f, l2 = 0.f, l3 = 0.f;
  float2 ac0 = make_float2(0, 0), ac1 = ac0, ac2 = ac0, ac3 = ac0;
  const int d = lane * 2;  // PV: lane owns dims d, d+1

  for (int it = 0; it < 16; ++it) {
    const int sloc = w * 64 + it * 4 + grp;
    const int s = s0 + sloc;
    // ---- K row (pointer-select for the updated position) ----
    const float4* kp =
        (const float4*)((s == cur) ? knew : (kbase + (long)s * HDD));
    float4 ka = kp[lg];
    float4 kb = kp[lg + 16];
    // ---- V rows for this iter's 4 keys (independent stream) ----
    const int sb = s0 + w * 64 + it * 4;
    const float* vr0 = (sb + 0 == cur) ? vnew : (vbase + (long)(sb + 0) * HDD);
    const float* vr1 = (sb + 1 == cur) ? vnew : (vbase + (long)(sb + 1) * HDD);
    const float* vr2 = (sb + 2 == cur) ? vnew : (vbase + (long)(sb + 2) * HDD);
    const float* vr3 = (sb + 3 == cur) ? vnew : (vbase + (long)(sb + 3) * HDD);
    float2 v0 = *(const float2*)(vr0 + d);
    float2 v1 = *(const float2*)(vr1 + d);
    float2 v2 = *(const float2*)(vr2 + d);
    float2 v3 = *(const float2*)(vr3 + d);

    float dots[GG];
#pragma unroll
    for (int g = 0; g < GG; ++g) {
      dots[g] = ka.x * qa[g].x + ka.y * qa[g].y + ka.z * qa[g].z +
                ka.w * qa[g].w + kb.x * qb[g].x + kb.y * qb[g].y +
                kb.z * qb[g].z + kb.w * qb[g].w;
    }
#pragma unroll
    for (int mm = 1; mm < 16; mm <<= 1) {
#pragma unroll
      for (int g = 0; g < GG; ++g) dots[g] += __shfl_xor(dots[g], mm);
    }
    // score (valid on every lane of the group after butterfly)
    float4 mv = mkp[sloc];
    float4 sv;
    sv.x = fmaf(dots[0], scale, mv.x);
    sv.y = fmaf(dots[1], scale, mv.y);
    sv.z = fmaf(dots[2], scale, mv.z);
    sv.w = fmaf(dots[3], scale, mv.w);
    // broadcast the 4 keys' scores to all lanes
    float4 sj0, sj1, sj2, sj3;
    sj0.x = __shfl(sv.x, 0);  sj0.y = __shfl(sv.y, 0);
    sj0.z = __shfl(sv.z, 0);  sj0.w = __shfl(sv.w, 0);
    sj1.x = __shfl(sv.x, 16); sj1.y = __shfl(sv.y, 16);
    sj1.z = __shfl(sv.z, 16); sj1.w = __shfl(sv.w, 16);
    sj2.x = __shfl(sv.x, 32); sj2.y = __shfl(sv.y, 32);
    sj2.z = __shfl(sv.z, 32); sj2.w = __shfl(sv.w, 32);
    sj3.x = __shfl(sv.x, 48); sj3.y = __shfl(sv.y, 48);
    sj3.z = __shfl(sv.z, 48); sj3.w = __shfl(sv.w, 48);
    // per-g new max across the 4 keys
    float nm0 = fmaxf(fmaxf(sj0.x, sj1.x), fmaxf(sj2.x, sj3.x));
    float nm1 = fmaxf(fmaxf(sj0.y, sj1.y), fmaxf(sj2.y, sj3.y));
    float nm2 = fmaxf(fmaxf(sj0.z, sj1.z), fmaxf(sj2.z, sj3.z));
    float nm3 = fmaxf(fmaxf(sj0.w, sj1.w), fmaxf(sj2.w, sj3.w));
    // defer-max rescale (wave-uniform branch)
    if (nm0 > m0 + 8.f || nm1 > m1 + 8.f || nm2 > m2 + 8.f ||
        nm3 > m3 + 8.f) {
      float M2, f;
      M2 = fmaxf(m0, nm0); f = __expf(m0 - M2);
      l0 *= f; ac0.x *= f; ac0.y *= f; m0 = M2;
      M2 = fmaxf(m1, nm1); f = __expf(m1 - M2);
      l1 *= f; ac1.x *= f; ac1.y *= f; m1 = M2;
      M2 = fmaxf(m2, nm2); f = __expf(m2 - M2);
      l2 *= f; ac2.x *= f; ac2.y *= f; m2 = M2;
      M2 = fmaxf(m3, nm3); f = __expf(m3 - M2);
      l3 *= f; ac3.x *= f; ac3.y *= f; m3 = M2;
    }
    // p = exp(s - m), accumulate l and PV
    float p00 = __expf(sj0.x - m0), p10 = __expf(sj1.x - m0),
          p20 = __expf(sj2.x - m0), p30 = __expf(sj3.x - m0);
    float p01 = __expf(sj0.y - m1), p11 = __expf(sj1.y - m1),
          p21 = __expf(sj2.y - m1), p31 = __expf(sj3.y - m1);
    float p02 = __expf(sj0.z - m2), p12 = __expf(sj1.z - m2),
          p22 = __expf(sj2.z - m2), p32 = __expf(sj3.z - m2);
    float p03 = __expf(sj0.w - m3), p13 = __expf(sj1.w - m3),
          p23 = __expf(sj2.w - m3), p33 = __expf(sj3.w - m3);
    l0 += (p00 + p10) + (p20 + p30);
    l1 += (p01 + p11) + (p21 + p31);
    l2 += (p02 + p12) + (p22 + p32);
    l3 += (p03 + p13) + (p23 + p33);
    ac0.x = fmaf(p00, v0.x, fmaf(p10, v1.x, fmaf(p20, v2.x, fmaf(p30, v3.x, ac0.x))));
    ac0.y = fmaf(p00, v0.y, fmaf(p10, v1.y, fmaf(p20, v2.y, fmaf(p30, v3.y, ac0.y))));
    ac1.x = fmaf(p01, v0.x, fmaf(p11, v1.x, fmaf(p21, v2.x, fmaf(p31, v3.x, ac1.x))));
    ac1.y = fmaf(p01, v0.y, fmaf(p11, v1.y, fmaf(p21, v2.y, fmaf(p31, v3.y, ac1.y))));
    ac2.x = fmaf(p02, v0.x, fmaf(p12, v1.x, fmaf(p22, v2.x, fmaf(p32, v3.x, ac2.x))));
    ac2.y = fmaf(p02, v0.y, fmaf(p12, v1.y, fmaf(p22, v2.y, fmaf(p32, v3.y, ac2.y))));
    ac3.x = fmaf(p03, v0.x, fmaf(p13, v1.x, fmaf(p23, v2.x, fmaf(p33, v3.x, ac3.x))));
    ac3.y = fmaf(p03, v0.y, fmaf(p13, v1.y, fmaf(p23, v2.y, fmaf(p33, v3.y, ac3.y))));
  }

  // ---- write wave partials to LDS ----
  wacc[w][0][d] = ac0.x; wacc[w][0][d + 1] = ac0.y;
  wacc[w][1][d] = ac1.x; wacc[w][1][d + 1] = ac1.y;
  wacc[w][2][d] = ac2.x; wacc[w][2][d + 1] = ac2.y;
  wacc[w][3][d] = ac3.x; wacc[w][3][d + 1] = ac3.y;
  if (lane == 0) {
    wml[w][0][0] = m0; wml[w][0][1] = l0;
    wml[w][1][0] = m1; wml[w][1][1] = l1;
    wml[w][2][0] = m2; wml[w][2][1] = l2;
    wml[w][3][0] = m3; wml[w][3][1] = l3;
  }
  __syncthreads();

  // ---- cross-wave combine: thread (g = t>>6, dims (t&63)*2) ----
  {
    const int g = t >> 6;
    const int dd = (t & 63) * 2;
    float Mg = fmaxf(fmaxf(wml[0][g][0], wml[1][g][0]),
                     fmaxf(wml[2][g][0], wml[3][g][0]));
    float Lg = 0.f, a0 = 0.f, a1 = 0.f;
#pragma unroll
    for (int ww = 0; ww < 4; ++ww) {
      float f = __expf(wml[ww][g][0] - Mg);
      Lg = fmaf(wml[ww][g][1], f, Lg);
      a0 = fmaf(f, wacc[ww][g][dd], a0);
      a1 = fmaf(f, wacc[ww][g][dd + 1], a1);
    }
    const long pidx = ((long)(b * NHH + kv * GG + g)) * NSPLIT + split;
    pacc[pidx * HDD + dd] = a0;
    pacc[pidx * HDD + dd + 1] = a1;
    if ((t & 63) == 0) {
      pm[pidx] = Mg;
      pl[pidx] = Lg;
    }
  }
}

// ============ combine split partials -> ctx =================================
__global__ __launch_bounds__(128) void attn_combine(
    const float* __restrict__ pm, const float* __restrict__ pl,
    const float* __restrict__ pacc, float* __restrict__ ctx) {
  const int bh = blockIdx.x;
  const int d = threadIdx.x;
  float M = -1e30f;
#pragma unroll
  for (int i = 0; i < NSPLIT; ++i) M = fmaxf(M, pm[bh * NSPLIT + i]);
  float L = 0.f, a = 0.f;
#pragma unroll
  for (int i = 0; i < NSPLIT; ++i) {
    float wexp = __expf(pm[bh * NSPLIT + i] - M);
    L += pl[bh * NSPLIT + i] * wexp;
    a += wexp * pacc[((long)bh * NSPLIT + i) * HDD + d];
  }
  ctx[(long)bh * HDD + d] = a / L;
}

extern "C" void kernel_launch(void* const* d_in, const int* in_sizes, int n_in,
                              void* d_out, int out_size, void* d_ws,
                              size_t ws_size, hipStream_t stream) {
  const float* x = (const float*)d_in[0];
  const float* wqkv = (const float*)d_in[1];
  const float* wo = (const float*)d_in[2];
  const float* rot = (const float*)d_in[3];
  const float* cache_k = (const float*)d_in[4];
  const float* cache_v = (const float*)d_in[5];
  const float* mask = (const float*)d_in[6];
  const int* curpos = (const int*)d_in[7];
  float* out = (float*)d_out;

  float* ws = (float*)d_ws;
  float* xqkv = ws;               // 196608
  float* q_rot = xqkv + 196608;   // 131072
  float* k_rot = q_rot + 131072;  // 32768
  float* pm = k_rot + 32768;      // 16384
  float* pl = pm + 16384;         // 16384
  float* ctx = pl + 16384;        // 131072
  float* big = ctx + 131072;      // 3145728 (gemm partials / pacc, shared)
  (void)in_sizes; (void)n_in; (void)out_size; (void)ws_size;

  hipLaunchKernelGGL(skinny_gemm_part, dim3(QKVC / 128, KSPB), dim3(256), 0,
                     stream, x, wqkv, big, DD, QKVC);
  hipLaunchKernelGGL(reduce_part, dim3((BB * QKVC) / 256), dim3(256), 0,
                     stream, big, xqkv, (long)BB * QKVC);
  hipLaunchKernelGGL(rotary_kernel, dim3(BB * NHH + BB * NKVV), dim3(128), 0,
                     stream, xqkv, rot, q_rot, k_rot);
  hipLaunchKernelGGL(attn_fused, dim3(BB * NKVV * NSPLIT), dim3(256), 0,
                     stream, q_rot, k_rot, xqkv, cache_k, cache_v, mask,
                     curpos, pm, pl, big);
  hipLaunchKernelGGL(attn_combine, dim3(BB * NHH), dim3(128), 0, stream, pm,
                     pl, big, ctx);
  hipLaunchKernelGGL(skinny_gemm_part, dim3(DD / 128, KSPB), dim3(256), 0,
                     stream, ctx, wo, big, DD, DD);
  hipLaunchKernelGGL(reduce_part, dim3((BB * DD) / 256), dim3(256), 0, stream,
                     big, out, (long)BB * DD);
}